// Round 3
// baseline (981.127 us; speedup 1.0000x reference)
//
#include <hip/hip_runtime.h>

#define NROWS 262144
#define DD 64
#define D2 128
#define KK 512

// output offsets (floats)
#define O_ZQR 0
#define O_ZQI 16777216
#define O_LOSS 33554432
#define O_IDX 33816576
#define O_ENT 34078720
#define O_EMB 34078721
#define O_NCL 34144257
#define O_EMA 34144769

// numpy pairwise-8 final combine
__device__ __forceinline__ float comb8(const float r[8]) {
  return __fadd_rn(__fadd_rn(__fadd_rn(r[0], r[1]), __fadd_rn(r[2], r[3])),
                   __fadd_rn(__fadd_rn(r[4], r[5]), __fadd_rn(r[6], r[7])));
}

// ---------------- K1: zero dw/n_total, compute y_sq (numpy pairwise-8 replica)
__global__ __launch_bounds__(256) void prep_kernel(const float* __restrict__ emb,
    float* __restrict__ ysq, int* __restrict__ nt, float* __restrict__ dw) {
  int t = blockIdx.x * 256 + threadIdx.x;   // 65536 threads
  dw[t] = 0.f;
  if (t < KK) {
    nt[t] = 0;
    const float* a = emb + t * D2;
    float r[8];
#pragma unroll
    for (int q = 0; q < 8; ++q) { float v = a[q]; r[q] = __fmul_rn(v, v); }
    for (int m = 1; m < 16; ++m)
#pragma unroll
      for (int q = 0; q < 8; ++q) { float v = a[8 * m + q]; r[q] = __fadd_rn(r[q], __fmul_rn(v, v)); }
    ysq[t] = comb8(r);
  }
}

// ---------------- K2: main — distances, argmin, zq_st, loss, indices, n_total
#define BM 64
#define CC 64
#define SZ 132   // padded LDS row stride (floats): bank-conflict-free b128 reads

__global__ __launch_bounds__(256, 2) void vq_main(
    const float* __restrict__ zr, const float* __restrict__ zi,
    const float* __restrict__ emb, const float* __restrict__ ysq,
    float* __restrict__ out_zqr, float* __restrict__ out_zqi,
    float* __restrict__ out_loss, float* __restrict__ out_idx,
    int* __restrict__ nt) {
  __shared__ __align__(16) float zs[BM * SZ];
  __shared__ __align__(16) float ws[CC * SZ];
  __shared__ int idxr[BM];
  const int tid = threadIdx.x;
  const int rowBase = blockIdx.x * BM;
  const int cg = tid & 15;   // 16 code-groups
  const int rg = tid >> 4;   // 16 row-groups

  // stage z tile: zs[row][0..63]=real, [64..127]=imag
#pragma unroll
  for (int r = 0; r < 8; ++r) {
    int fidx = r * 256 + tid;     // float4 index, 2048 total
    int row = fidx >> 5;
    int g = fidx & 31;
    float4 v;
    if (g < 16) v = *(const float4*)(zr + (size_t)(rowBase + row) * DD + g * 4);
    else        v = *(const float4*)(zi + (size_t)(rowBase + row) * DD + (g - 16) * 4);
    *(float4*)&zs[row * SZ + g * 4] = v;
  }
  __syncthreads();

  // x_sq per row: numpy pairwise-8 replica; lanes 0..15 of each wave do 16 rows
  const int wave = tid >> 6;
  const int lane = tid & 63;
  float myxq = 0.f;
  if (lane < 16) {
    int row = wave * 4 + (lane & 3) + 16 * (lane >> 2);
    const float* zp = zs + row * SZ;
    float r8[8];
#pragma unroll
    for (int q = 0; q < 8; ++q) { float z = zp[q]; r8[q] = __fmul_rn(z, z); }
    for (int m = 1; m < 16; ++m)
#pragma unroll
      for (int q = 0; q < 8; ++q) { float z = zp[8 * m + q]; r8[q] = __fadd_rn(r8[q], __fmul_rn(z, z)); }
    myxq = comb8(r8);
  }
  float xqv[4];
  {
    int a = rg & 3;
#pragma unroll
    for (int i = 0; i < 4; ++i) xqv[i] = __shfl(myxq, a + 4 * i, 64);
  }

  float bmin[4] = {3.4e38f, 3.4e38f, 3.4e38f, 3.4e38f};
  int bidx[4] = {0, 0, 0, 0};

  for (int ch = 0; ch < 8; ++ch) {
    __syncthreads();   // previous chunk's compute done before overwriting ws
#pragma unroll
    for (int r = 0; r < 8; ++r) {
      int fidx = r * 256 + tid;
      int c = fidx >> 5;
      int g = fidx & 31;
      float4 v = *(const float4*)(emb + (size_t)(ch * CC + c) * D2 + g * 4);
      *(float4*)&ws[c * SZ + g * 4] = v;
    }
    __syncthreads();
    float yv[4];
#pragma unroll
    for (int j = 0; j < 4; ++j) yv[j] = ysq[ch * CC + cg + 16 * j];

    float acc[4][4];
#pragma unroll
    for (int i = 0; i < 4; ++i)
#pragma unroll
      for (int j = 0; j < 4; ++j) acc[i][j] = 0.f;

    // dot over d=0..127 sequential fmaf chain per (row,code)
#pragma unroll 8
    for (int g = 0; g < 32; ++g) {
      float4 za[4], wb[4];
#pragma unroll
      for (int i = 0; i < 4; ++i) za[i] = *(const float4*)&zs[(rg + 16 * i) * SZ + g * 4];
#pragma unroll
      for (int j = 0; j < 4; ++j) wb[j] = *(const float4*)&ws[(cg + 16 * j) * SZ + g * 4];
#pragma unroll
      for (int i = 0; i < 4; ++i)
#pragma unroll
        for (int j = 0; j < 4; ++j) {
          acc[i][j] = fmaf(za[i].x, wb[j].x, acc[i][j]);
          acc[i][j] = fmaf(za[i].y, wb[j].y, acc[i][j]);
          acc[i][j] = fmaf(za[i].z, wb[j].z, acc[i][j]);
          acc[i][j] = fmaf(za[i].w, wb[j].w, acc[i][j]);
        }
    }

#pragma unroll
    for (int i = 0; i < 4; ++i)
#pragma unroll
      for (int j = 0; j < 4; ++j) {     // j ascending == code ascending (first-min)
        int code = ch * CC + cg + 16 * j;
        float t = __fadd_rn(xqv[i], yv[j]);          // fl(x_sq + y_sq)
        float dist = fmaf(-2.f, acc[i][j], t);       // fl(t - 2*dot), 2*dot exact
        if (dist < bmin[i]) { bmin[i] = dist; bidx[i] = code; }
      }
  }

  // cross-thread argmin reduce: (val, idx) lexicographic, first-min semantics
  __syncthreads();
  float2* red = (float2*)ws;
#pragma unroll
  for (int i = 0; i < 4; ++i) {
    int row = rg + 16 * i;
    red[row * 16 + cg] = make_float2(bmin[i], (float)bidx[i]);
  }
  __syncthreads();
  if (tid < BM) {
    float2 best = red[tid * 16];
#pragma unroll
    for (int c = 1; c < 16; ++c) {
      float2 v = red[tid * 16 + c];
      if (v.x < best.x || (v.x == best.x && v.y < best.y)) best = v;
    }
    int bi = (int)best.y;
    out_idx[rowBase + tid] = best.y;
    atomicAdd(&nt[bi], 1);
    idxr[tid] = bi;
  }
  __syncthreads();

  // zq_st = z + (e - z), elementwise fp32 replica; coalesced float4 stores
  {
    int row = tid >> 2, q = tid & 3;
    int bi = idxr[row];
    const float* erow = emb + bi * D2;
    const float* zp = zs + row * SZ;
    float* outp;
    if (q < 2) outp = out_zqr + (size_t)(rowBase + row) * DD + q * 32;
    else       outp = out_zqi + (size_t)(rowBase + row) * DD + (q - 2) * 32;
#pragma unroll
    for (int m = 0; m < 8; ++m) {
      int d = q * 32 + m * 4;
      float4 e4 = *(const float4*)(erow + d);
      float4 z4 = *(const float4*)(zp + d);
      float4 o;
      o.x = __fadd_rn(z4.x, __fsub_rn(e4.x, z4.x));
      o.y = __fadd_rn(z4.y, __fsub_rn(e4.y, z4.y));
      o.z = __fadd_rn(z4.z, __fsub_rn(e4.z, z4.z));
      o.w = __fadd_rn(z4.w, __fsub_rn(e4.w, z4.w));
      *(float4*)(outp + m * 4) = o;
    }
  }

  // loss = 0.25 * mean((e - z)^2), numpy pairwise-8 replica, one thread/row
  if (tid < BM) {
    int bi = idxr[tid];
    const float* erow = emb + bi * D2;
    const float* zp = zs + tid * SZ;
    float r8[8];
#pragma unroll
    for (int q = 0; q < 8; ++q) {
      float df = __fsub_rn(erow[q], zp[q]);
      r8[q] = __fmul_rn(df, df);
    }
    for (int m = 1; m < 16; ++m)
#pragma unroll
      for (int q = 0; q < 8; ++q) {
        float df = __fsub_rn(erow[8 * m + q], zp[8 * m + q]);
        r8[q] = __fadd_rn(r8[q], __fmul_rn(df, df));
      }
    float S = comb8(r8);
    out_loss[rowBase + tid] = __fmul_rn(0.25f, S / 128.0f);   // /128, *0.25 both exact
  }
}

// ---------------- K3: dw segment-sum, LDS-staged per 32-col d-chunk
__global__ __launch_bounds__(256) void dw_scatter(const float* __restrict__ zr,
    const float* __restrict__ zi, const float* __restrict__ idxf,
    float* __restrict__ dw) {
  __shared__ float tab[KK * 32];
  int tid = threadIdx.x;
  int dc = blockIdx.x & 3;        // 4 d-chunks of 32
  int rb = blockIdx.x >> 2;       // 64 row-chunks of 4096
  for (int l = tid; l < KK * 32; l += 256) tab[l] = 0.f;
  __syncthreads();
  int r = tid >> 5, c = tid & 31;
  const float* zsrc = (dc < 2) ? zr : zi;
  int colBase = (dc & 1) * 32;
  int rowBase = rb * 4096;
  for (int it = 0; it < 512; ++it) {
    int row = rowBase + it * 8 + r;
    int idx = (int)idxf[row];
    float v = zsrc[(size_t)row * DD + colBase + c];
    atomicAdd(&tab[idx * 32 + c], v);
  }
  __syncthreads();
  for (int l = tid; l < KK * 32; l += 256) {
    int k = l >> 5, cc = l & 31;
    atomicAdd(&dw[k * D2 + dc * 32 + cc], tab[l]);
  }
}

// ---------------- K4: new_cluster, tot, cluster_size, entropy
__device__ float pw128(const float* a) {
  float r[8];
#pragma unroll
  for (int q = 0; q < 8; ++q) r[q] = a[q];
  for (int m = 1; m < 16; ++m)
#pragma unroll
    for (int q = 0; q < 8; ++q) r[q] = __fadd_rn(r[q], a[8 * m + q]);
  return comb8(r);
}

__global__ __launch_bounds__(512) void finalize_kernel(const int* __restrict__ nt,
    const float* __restrict__ ema_cs, float* __restrict__ out_ncl,
    float* __restrict__ out_ent, float* __restrict__ csize) {
  __shared__ float arr[KK];
  __shared__ float term[KK];
  __shared__ float tot_s;
  int t = threadIdx.x;
  float c = (float)nt[t];
  float newc = __fadd_rn(__fmul_rn(ema_cs[t], 0.99f), __fmul_rn(0.01f, c));
  out_ncl[t] = newc;
  arr[t] = newc;
  float p = c / 262144.f;   // exact
  term[t] = __fmul_rn(p, logf(__fadd_rn(p, 1e-10f)));
  __syncthreads();
  if (t == 0) {
    // numpy pairwise over 512 = ((pw128+pw128)+(pw128+pw128))
    float tot = __fadd_rn(__fadd_rn(pw128(arr), pw128(arr + 128)),
                          __fadd_rn(pw128(arr + 256), pw128(arr + 384)));
    tot_s = tot;
    float S = __fadd_rn(__fadd_rn(pw128(term), pw128(term + 128)),
                        __fadd_rn(pw128(term + 256), pw128(term + 384)));
    out_ent[0] = __fdiv_rn(-S, 6.2383246250395075f);  // / log(512)
  }
  __syncthreads();
  float tot = tot_s;
  float cs = __fmul_rn(__fdiv_rn(__fadd_rn(arr[t], 1e-5f), __fadd_rn(tot, 0.00512f)), tot);
  csize[t] = cs;
}

// ---------------- K5: new_ema_w, new_emb_w
__global__ __launch_bounds__(256) void ema_out_kernel(const float* __restrict__ ema_w,
    const float* __restrict__ dw, const float* __restrict__ csize,
    float* __restrict__ out_ema, float* __restrict__ out_emb) {
  int t = blockIdx.x * 256 + threadIdx.x;   // 65536
  float e = __fadd_rn(__fmul_rn(ema_w[t], 0.99f), __fmul_rn(0.01f, dw[t]));
  out_ema[t] = e;
  out_emb[t] = __fdiv_rn(e, csize[t >> 7]);
}

extern "C" void kernel_launch(void* const* d_in, const int* in_sizes, int n_in,
                              void* d_out, int out_size, void* d_ws, size_t ws_size,
                              hipStream_t stream) {
  const float* zr     = (const float*)d_in[0];
  const float* zi     = (const float*)d_in[1];
  const float* emb    = (const float*)d_in[2];
  const float* ema_cs = (const float*)d_in[3];
  const float* ema_w  = (const float*)d_in[4];
  float* out = (float*)d_out;

  float* wsf   = (float*)d_ws;
  float* ysq   = wsf;            // 512
  float* csize = wsf + 512;      // 512
  int*   nt    = (int*)(wsf + 1024);  // 512
  float* dw    = wsf + 1536;     // 65536

  prep_kernel<<<256, 256, 0, stream>>>(emb, ysq, nt, dw);
  vq_main<<<NROWS / BM, 256, 0, stream>>>(zr, zi, emb, ysq,
      out + O_ZQR, out + O_ZQI, out + O_LOSS, out + O_IDX, nt);
  dw_scatter<<<256, 256, 0, stream>>>(zr, zi, out + O_IDX, dw);
  finalize_kernel<<<1, 512, 0, stream>>>(nt, ema_cs, out + O_NCL, out + O_ENT, csize);
  ema_out_kernel<<<256, 256, 0, stream>>>(ema_w, dw, csize, out + O_EMA, out + O_EMB);
}

// Round 5
// 955.474 us; speedup vs baseline: 1.0268x; 1.0268x over previous
//
#include <hip/hip_runtime.h>

#define NROWS 262144
#define DD 64
#define D2 128
#define KK 512

// output offsets (floats)
#define O_ZQR 0
#define O_ZQI 16777216
#define O_LOSS 33554432
#define O_IDX 33816576
#define O_ENT 34078720
#define O_EMB 34078721
#define O_NCL 34144257
#define O_EMA 34144769

// numpy pairwise-8 final combine
__device__ __forceinline__ float comb8(const float r[8]) {
  return __fadd_rn(__fadd_rn(__fadd_rn(r[0], r[1]), __fadd_rn(r[2], r[3])),
                   __fadd_rn(__fadd_rn(r[4], r[5]), __fadd_rn(r[6], r[7])));
}

// ---------------- K1: zero dw/n_total, compute y_sq (numpy pairwise-8 replica)
__global__ __launch_bounds__(256) void prep_kernel(const float* __restrict__ emb,
    float* __restrict__ ysq, int* __restrict__ nt, float* __restrict__ dw) {
  int t = blockIdx.x * 256 + threadIdx.x;   // 65536 threads
  dw[t] = 0.f;
  if (t < KK) {
    nt[t] = 0;
    const float* a = emb + t * D2;
    float r[8];
#pragma unroll
    for (int q = 0; q < 8; ++q) { float v = a[q]; r[q] = __fmul_rn(v, v); }
    for (int m = 1; m < 16; ++m)
#pragma unroll
      for (int q = 0; q < 8; ++q) { float v = a[8 * m + q]; r[q] = __fadd_rn(r[q], __fmul_rn(v, v)); }
    ysq[t] = comb8(r);
  }
}

// ---------------- K2: main — distances, argmin, zq_st, loss, indices, n_total
// 8x8 register tile per thread; BM=128 rows, CC=128 codes per LDS chunk.
// LDS ~135 KB -> 1 block/CU; __launch_bounds__(256,1) frees VGPR budget.
#define BM 128
#define CC 128
#define NCH (KK / CC)
#define SZ 132   // stride: mult of 4 (float4 align), mod 32 == 4 (bank spread)

#define LOADOPS(ZA, WB, G)                                                    \
  _Pragma("unroll") for (int i = 0; i < 8; ++i)                               \
      ZA[i] = *(const float4*)&zs[(rg + 16 * i) * SZ + (G) * 4];              \
  _Pragma("unroll") for (int j = 0; j < 8; ++j)                               \
      WB[j] = *(const float4*)&ws[(cg + 16 * j) * SZ + (G) * 4];

#define FMAOPS(ZA, WB)                                                        \
  _Pragma("unroll") for (int i = 0; i < 8; ++i)                               \
  _Pragma("unroll") for (int j = 0; j < 8; ++j) {                             \
    acc[i][j] = fmaf(ZA[i].x, WB[j].x, acc[i][j]);                            \
    acc[i][j] = fmaf(ZA[i].y, WB[j].y, acc[i][j]);                            \
    acc[i][j] = fmaf(ZA[i].z, WB[j].z, acc[i][j]);                            \
    acc[i][j] = fmaf(ZA[i].w, WB[j].w, acc[i][j]);                            \
  }

__global__ __launch_bounds__(256, 1) void vq_main(
    const float* __restrict__ zr, const float* __restrict__ zi,
    const float* __restrict__ emb, const float* __restrict__ ysq,
    float* __restrict__ out_zqr, float* __restrict__ out_zqi,
    float* __restrict__ out_loss, float* __restrict__ out_idx,
    int* __restrict__ nt) {
  __shared__ __align__(16) float zs[BM * SZ];
  __shared__ __align__(16) float ws[CC * SZ];
  __shared__ float ysql[KK];
  __shared__ float xsql[BM];
  __shared__ int idxr[BM];
  const int tid = threadIdx.x;
  const int rowBase = blockIdx.x * BM;
  const int cg = tid & 15;   // 16 code-groups (codes cg + 16j)
  const int rg = tid >> 4;   // 16 row-groups  (rows  rg + 16i)

  // stage z tile: zs[row][0..63]=real, [64..127]=imag (16 float4 per thread)
#pragma unroll
  for (int r = 0; r < 16; ++r) {
    int fidx = r * 256 + tid;     // 4096 float4 total
    int row = fidx >> 5;
    int g = fidx & 31;
    float4 v;
    if (g < 16) v = *(const float4*)(zr + (size_t)(rowBase + row) * DD + g * 4);
    else        v = *(const float4*)(zi + (size_t)(rowBase + row) * DD + (g - 16) * 4);
    *(float4*)&zs[row * SZ + g * 4] = v;
  }
  ysql[tid] = ysq[tid];
  ysql[256 + tid] = ysq[256 + tid];
  __syncthreads();

  // x_sq per row (numpy pairwise-8 replica), one thread per row
  if (tid < BM) {
    const float* zp = zs + tid * SZ;
    float r8[8];
#pragma unroll
    for (int q = 0; q < 8; ++q) { float z = zp[q]; r8[q] = __fmul_rn(z, z); }
    for (int m = 1; m < 16; ++m)
#pragma unroll
      for (int q = 0; q < 8; ++q) { float z = zp[8 * m + q]; r8[q] = __fadd_rn(r8[q], __fmul_rn(z, z)); }
    xsql[tid] = comb8(r8);
  }
  __syncthreads();

  float xqv[8];
#pragma unroll
  for (int i = 0; i < 8; ++i) xqv[i] = xsql[rg + 16 * i];

  float bmin[8] = {3.4e38f, 3.4e38f, 3.4e38f, 3.4e38f, 3.4e38f, 3.4e38f, 3.4e38f, 3.4e38f};
  int bidx[8] = {0, 0, 0, 0, 0, 0, 0, 0};

#pragma unroll 1
  for (int ch = 0; ch < NCH; ++ch) {
    __syncthreads();   // previous chunk's compute done before overwriting ws
#pragma unroll
    for (int r = 0; r < 16; ++r) {
      int fidx = r * 256 + tid;
      int c = fidx >> 5;
      int g = fidx & 31;
      float4 v = *(const float4*)(emb + (size_t)(ch * CC + c) * D2 + g * 4);
      *(float4*)&ws[c * SZ + g * 4] = v;
    }
    __syncthreads();
    float yv[8];
#pragma unroll
    for (int j = 0; j < 8; ++j) yv[j] = ysql[ch * CC + cg + 16 * j];

    float acc[8][8];
#pragma unroll
    for (int i = 0; i < 8; ++i)
#pragma unroll
      for (int j = 0; j < 8; ++j) acc[i][j] = 0.f;

    // dot over d=0..127, sequential fmaf chain per (row,code);
    // register double-buffered g-loop (named A/B bufs: all-static indexing)
    float4 zaA[8], wbA[8], zaB[8], wbB[8];
    LOADOPS(zaA, wbA, 0)
#pragma unroll 1
    for (int g = 0; g < 30; g += 2) {
      LOADOPS(zaB, wbB, g + 1)
      FMAOPS(zaA, wbA)
      LOADOPS(zaA, wbA, g + 2)
      FMAOPS(zaB, wbB)
    }
    LOADOPS(zaB, wbB, 31)
    FMAOPS(zaA, wbA)
    FMAOPS(zaB, wbB)

#pragma unroll
    for (int i = 0; i < 8; ++i)
#pragma unroll
      for (int j = 0; j < 8; ++j) {     // j ascending == code ascending (first-min)
        int code = ch * CC + cg + 16 * j;
        float t = __fadd_rn(xqv[i], yv[j]);          // fl(x_sq + y_sq)
        float dist = fmaf(-2.f, acc[i][j], t);       // fl(t - 2*dot), 2*dot exact
        if (dist < bmin[i]) { bmin[i] = dist; bidx[i] = code; }
      }
  }

  // cross-thread argmin reduce: (val, idx) lexicographic, first-min semantics
  __syncthreads();
  float2* red = (float2*)ws;
#pragma unroll
  for (int i = 0; i < 8; ++i) {
    int row = rg + 16 * i;
    red[row * 16 + cg] = make_float2(bmin[i], (float)bidx[i]);
  }
  __syncthreads();
  if (tid < BM) {
    float2 best = red[tid * 16];
#pragma unroll
    for (int c = 1; c < 16; ++c) {
      float2 v = red[tid * 16 + c];
      if (v.x < best.x || (v.x == best.x && v.y < best.y)) best = v;
    }
    int bi = (int)best.y;
    out_idx[rowBase + tid] = best.y;
    atomicAdd(&nt[bi], 1);
    idxr[tid] = bi;
  }
  __syncthreads();

  // zq_st = z + (e - z): 16 coalesced passes, 16 lanes cover one row's half
  {
    int m = tid & 15;        // float4 index within 64-float half
    int rsub = tid >> 4;     // 16 rows per pass
#pragma unroll
    for (int pass = 0; pass < 16; ++pass) {
      int half = pass & 1;             // 0=real, 1=imag
      int row = (pass >> 1) * 16 + rsub;
      int bi = idxr[row];
      float4 e4 = *(const float4*)(emb + (size_t)bi * D2 + half * DD + m * 4);
      float4 z4 = *(const float4*)&zs[row * SZ + half * DD + m * 4];
      float4 o;
      o.x = __fadd_rn(z4.x, __fsub_rn(e4.x, z4.x));
      o.y = __fadd_rn(z4.y, __fsub_rn(e4.y, z4.y));
      o.z = __fadd_rn(z4.z, __fsub_rn(e4.z, z4.z));
      o.w = __fadd_rn(z4.w, __fsub_rn(e4.w, z4.w));
      float* outp = half ? (out_zqi + (size_t)(rowBase + row) * DD + m * 4)
                         : (out_zqr + (size_t)(rowBase + row) * DD + m * 4);
      *(float4*)outp = o;
    }
  }

  // loss = 0.25 * mean((e - z)^2), numpy pairwise-8 replica, one thread/row
  if (tid < BM) {
    int bi = idxr[tid];
    const float* erow = emb + (size_t)bi * D2;
    const float* zp = zs + tid * SZ;
    float r8[8];
#pragma unroll
    for (int q = 0; q < 8; ++q) {
      float df = __fsub_rn(erow[q], zp[q]);
      r8[q] = __fmul_rn(df, df);
    }
    for (int m = 1; m < 16; ++m)
#pragma unroll
      for (int q = 0; q < 8; ++q) {
        float df = __fsub_rn(erow[8 * m + q], zp[8 * m + q]);
        r8[q] = __fadd_rn(r8[q], __fmul_rn(df, df));
      }
    float S = comb8(r8);
    out_loss[rowBase + tid] = __fmul_rn(0.25f, S / 128.0f);   // /128, *0.25 both exact
  }
}

// ---------------- K3: dw segment-sum, LDS-staged per 32-col d-chunk
// 1024 blocks (4 d-chunks x 256 row-chunks of 1024): 2 blocks/CU (64KB LDS),
// software-pipelined loads.
__global__ __launch_bounds__(256) void dw_scatter(const float* __restrict__ zr,
    const float* __restrict__ zi, const float* __restrict__ idxf,
    float* __restrict__ dw) {
  __shared__ float tab[KK * 32];
  int tid = threadIdx.x;
  int dc = blockIdx.x & 3;        // 4 d-chunks of 32
  int rb = blockIdx.x >> 2;       // 256 row-chunks of 1024
  for (int l = tid; l < KK * 32; l += 256) tab[l] = 0.f;
  __syncthreads();
  int r = tid >> 5, c = tid & 31;
  const float* zsrc = (dc < 2) ? zr : zi;
  int colBase = (dc & 1) * 32;
  int rowBase = rb * 1024;
  int row = rowBase + r;
  int idx = (int)idxf[row];
  float v = zsrc[(size_t)row * DD + colBase + c];
  for (int it = 0; it < 127; ++it) {
    int nrow = rowBase + (it + 1) * 8 + r;
    int nidx = (int)idxf[nrow];
    float nv = zsrc[(size_t)nrow * DD + colBase + c];
    atomicAdd(&tab[idx * 32 + c], v);
    idx = nidx; v = nv;
  }
  atomicAdd(&tab[idx * 32 + c], v);
  __syncthreads();
  for (int l = tid; l < KK * 32; l += 256) {
    int k = l >> 5, cc = l & 31;
    atomicAdd(&dw[k * D2 + dc * 32 + cc], tab[l]);
  }
}

// ---------------- K4: new_cluster, tot, cluster_size, entropy
__device__ float pw128(const float* a) {
  float r[8];
#pragma unroll
  for (int q = 0; q < 8; ++q) r[q] = a[q];
  for (int m = 1; m < 16; ++m)
#pragma unroll
    for (int q = 0; q < 8; ++q) r[q] = __fadd_rn(r[q], a[8 * m + q]);
  return comb8(r);
}

__global__ __launch_bounds__(512) void finalize_kernel(const int* __restrict__ nt,
    const float* __restrict__ ema_cs, float* __restrict__ out_ncl,
    float* __restrict__ out_ent, float* __restrict__ csize) {
  __shared__ float arr[KK];
  __shared__ float term[KK];
  __shared__ float tot_s;
  int t = threadIdx.x;
  float c = (float)nt[t];
  float newc = __fadd_rn(__fmul_rn(ema_cs[t], 0.99f), __fmul_rn(0.01f, c));
  out_ncl[t] = newc;
  arr[t] = newc;
  float p = c / 262144.f;   // exact
  term[t] = __fmul_rn(p, logf(__fadd_rn(p, 1e-10f)));
  __syncthreads();
  if (t == 0) {
    float tot = __fadd_rn(__fadd_rn(pw128(arr), pw128(arr + 128)),
                          __fadd_rn(pw128(arr + 256), pw128(arr + 384)));
    tot_s = tot;
    float S = __fadd_rn(__fadd_rn(pw128(term), pw128(term + 128)),
                        __fadd_rn(pw128(term + 256), pw128(term + 384)));
    out_ent[0] = __fdiv_rn(-S, 6.2383246250395075f);  // / log(512)
  }
  __syncthreads();
  float tot = tot_s;
  float cs = __fmul_rn(__fdiv_rn(__fadd_rn(arr[t], 1e-5f), __fadd_rn(tot, 0.00512f)), tot);
  csize[t] = cs;
}

// ---------------- K5: new_ema_w, new_emb_w
__global__ __launch_bounds__(256) void ema_out_kernel(const float* __restrict__ ema_w,
    const float* __restrict__ dw, const float* __restrict__ csize,
    float* __restrict__ out_ema, float* __restrict__ out_emb) {
  int t = blockIdx.x * 256 + threadIdx.x;   // 65536
  float e = __fadd_rn(__fmul_rn(ema_w[t], 0.99f), __fmul_rn(0.01f, dw[t]));
  out_ema[t] = e;
  out_emb[t] = __fdiv_rn(e, csize[t >> 7]);
}

extern "C" void kernel_launch(void* const* d_in, const int* in_sizes, int n_in,
                              void* d_out, int out_size, void* d_ws, size_t ws_size,
                              hipStream_t stream) {
  const float* zr     = (const float*)d_in[0];
  const float* zi     = (const float*)d_in[1];
  const float* emb    = (const float*)d_in[2];
  const float* ema_cs = (const float*)d_in[3];
  const float* ema_w  = (const float*)d_in[4];
  float* out = (float*)d_out;

  float* wsf   = (float*)d_ws;
  float* ysq   = wsf;            // 512
  float* csize = wsf + 512;      // 512
  int*   nt    = (int*)(wsf + 1024);  // 512
  float* dw    = wsf + 1536;     // 65536

  prep_kernel<<<256, 256, 0, stream>>>(emb, ysq, nt, dw);
  vq_main<<<NROWS / BM, 256, 0, stream>>>(zr, zi, emb, ysq,
      out + O_ZQR, out + O_ZQI, out + O_LOSS, out + O_IDX, nt);
  dw_scatter<<<1024, 256, 0, stream>>>(zr, zi, out + O_IDX, dw);
  finalize_kernel<<<1, 512, 0, stream>>>(nt, ema_cs, out + O_NCL, out + O_ENT, csize);
  ema_out_kernel<<<256, 256, 0, stream>>>(ema_w, dw, csize, out + O_EMA, out + O_EMB);
}

// Round 6
// 796.042 us; speedup vs baseline: 1.2325x; 1.2003x over previous
//
#include <hip/hip_runtime.h>

#define NROWS 262144
#define DD 64
#define D2 128
#define KK 512

// output offsets (floats)
#define O_ZQR 0
#define O_ZQI 16777216
#define O_LOSS 33554432
#define O_IDX 33816576
#define O_ENT 34078720
#define O_EMB 34078721
#define O_NCL 34144257
#define O_EMA 34144769

typedef __bf16 bf16x8 __attribute__((ext_vector_type(8)));
typedef float f32x4 __attribute__((ext_vector_type(4)));

// numpy pairwise-8 final combine
__device__ __forceinline__ float comb8(const float r[8]) {
  return __fadd_rn(__fadd_rn(__fadd_rn(r[0], r[1]), __fadd_rn(r[2], r[3])),
                   __fadd_rn(__fadd_rn(r[4], r[5]), __fadd_rn(r[6], r[7])));
}

// fp32 -> bf16 RNE (bit trick; no NaN/inf in data)
__device__ __forceinline__ ushort f2bf(float x) {
  union { float f; unsigned u; } a; a.f = x;
  unsigned r = (a.u + 0x7FFFu + ((a.u >> 16) & 1u)) >> 16;
  return (ushort)r;
}

// ---------------- K1: zero dw/n_total, compute y_sq (numpy pairwise-8 replica)
__global__ __launch_bounds__(256) void prep_kernel(const float* __restrict__ emb,
    float* __restrict__ ysq, int* __restrict__ nt, float* __restrict__ dw) {
  int t = blockIdx.x * 256 + threadIdx.x;   // 65536 threads
  dw[t] = 0.f;
  if (t < KK) {
    nt[t] = 0;
    const float* a = emb + t * D2;
    float r[8];
#pragma unroll
    for (int q = 0; q < 8; ++q) { float v = a[q]; r[q] = __fmul_rn(v, v); }
    for (int m = 1; m < 16; ++m)
#pragma unroll
      for (int q = 0; q < 8; ++q) { float v = a[8 * m + q]; r[q] = __fadd_rn(r[q], __fmul_rn(v, v)); }
    ysq[t] = comb8(r);
  }
}

// ---------------- K2: MFMA filter + exact rescore + epilogue
// 512 thr / 8 waves, 128 rows/block, codes in 4 chunks of 128, K=128 (4 MFMA steps).
// Phase 0: s~ = ysq - 2*(z_bf16 . w_bf16) via MFMA -> per-row min.
// Phase 1: recompute s~, list codes with s~ <= min + DELTA (superset of exact
//          fl-argmin: bf16 error ~7e-5 << DELTA). Rescore listed codes with the
//          exact scalar fp32 replica; lex-first-min per row.
#define BMR 128
#define DELTA 1e-3f
#define LCAP 2048

__global__ __launch_bounds__(512, 2) void vq_mfma(
    const float* __restrict__ zr, const float* __restrict__ zi,
    const float* __restrict__ emb, const float* __restrict__ ysq,
    float* __restrict__ out_zqr, float* __restrict__ out_zqi,
    float* __restrict__ out_loss, float* __restrict__ out_idx,
    int* __restrict__ nt) {
  __shared__ __align__(16) float zf[BMR * 132];      // z fp32, padded stride
  __shared__ __align__(16) ushort Ab[BMR * 136];     // z bf16, 272B rows
  __shared__ __align__(16) ushort Bb[128 * 136];     // codebook chunk bf16
  __shared__ float ysql[KK];
  __shared__ float xsql[BMR];
  __shared__ float rowmin[BMR];
  __shared__ ushort lst[LCAP];
  __shared__ float rD[LCAP];
  __shared__ int cnt;
  __shared__ int idxr[BMR];

  const int tid = threadIdx.x;
  const int rowBase = blockIdx.x * BMR;
  const int wv = tid >> 6;
  const int lane = tid & 63;

  // stage z tile fp32: zf[row][0..63]=real, [64..127]=imag
#pragma unroll
  for (int r = 0; r < 8; ++r) {
    int fidx = r * 512 + tid;       // 4096 float4
    int row = fidx >> 5, g = fidx & 31;
    float4 v;
    if (g < 16) v = *(const float4*)(zr + (size_t)(rowBase + row) * DD + g * 4);
    else        v = *(const float4*)(zi + (size_t)(rowBase + row) * DD + (g - 16) * 4);
    *(float4*)&zf[row * 132 + g * 4] = v;
  }
  ysql[tid] = ysq[tid];
  if (tid == 0) cnt = 0;
  __syncthreads();

  // x_sq per row (numpy pairwise-8 replica)
  if (tid < BMR) {
    const float* zp = zf + tid * 132;
    float r8[8];
#pragma unroll
    for (int q = 0; q < 8; ++q) { float z = zp[q]; r8[q] = __fmul_rn(z, z); }
    for (int m = 1; m < 16; ++m)
#pragma unroll
      for (int q = 0; q < 8; ++q) { float z = zp[8 * m + q]; r8[q] = __fadd_rn(r8[q], __fmul_rn(z, z)); }
    xsql[tid] = comb8(r8);
  }
  // convert z -> bf16 A-tile
  for (int l = tid; l < BMR * 32; l += 512) {
    int row = l >> 5, seg = l & 31;
    const float* zp = &zf[row * 132 + seg * 4];
    ushort4 u;
    u.x = f2bf(zp[0]); u.y = f2bf(zp[1]); u.z = f2bf(zp[2]); u.w = f2bf(zp[3]);
    *(ushort4*)&Ab[row * 136 + seg * 4] = u;
  }
  __syncthreads();

  // A-fragments (persistent): lane holds row (lane&15), k-octet (lane>>4)
  bf16x8 af[4];
#pragma unroll
  for (int t = 0; t < 4; ++t)
    af[t] = *(const bf16x8*)&Ab[(16 * wv + (lane & 15)) * 136 + t * 32 + (lane >> 4) * 8];

  float m4[4] = {3.4e38f, 3.4e38f, 3.4e38f, 3.4e38f};

#pragma unroll 1
  for (int phase = 0; phase < 2; ++phase) {
#pragma unroll 1
    for (int c = 0; c < 4; ++c) {
      __syncthreads();   // prior chunk's MFMA reads done
      // stage codebook chunk c as bf16 (emb is L2-resident)
      for (int l = tid; l < 128 * 32; l += 512) {
        int code = l >> 5, seg = l & 31;
        float4 v = *(const float4*)(emb + (size_t)(c * 128 + code) * D2 + seg * 4);
        ushort4 u;
        u.x = f2bf(v.x); u.y = f2bf(v.y); u.z = f2bf(v.z); u.w = f2bf(v.w);
        *(ushort4*)&Bb[code * 136 + seg * 4] = u;
      }
      __syncthreads();

      f32x4 acc[8];
#pragma unroll
      for (int j = 0; j < 8; ++j) acc[j] = (f32x4){0.f, 0.f, 0.f, 0.f};
#pragma unroll
      for (int j = 0; j < 8; ++j)
#pragma unroll
        for (int t = 0; t < 4; ++t) {
          bf16x8 bv = *(const bf16x8*)&Bb[(j * 16 + (lane & 15)) * 136 + t * 32 + (lane >> 4) * 8];
          acc[j] = __builtin_amdgcn_mfma_f32_16x16x32_bf16(af[t], bv, acc[j], 0, 0, 0);
        }

      if (phase == 0) {
#pragma unroll
        for (int j = 0; j < 8; ++j) {
          float y = ysql[c * 128 + j * 16 + (lane & 15)];
#pragma unroll
          for (int r = 0; r < 4; ++r)
            m4[r] = fminf(m4[r], fmaf(-2.f, acc[j][r], y));
        }
      } else {
#pragma unroll
        for (int j = 0; j < 8; ++j) {
          int code = c * 128 + j * 16 + (lane & 15);
          float y = ysql[code];
#pragma unroll
          for (int r = 0; r < 4; ++r) {
            float s = fmaf(-2.f, acc[j][r], y);
            int row = 16 * wv + (lane >> 4) * 4 + r;
            if (s <= rowmin[row] + DELTA) {
              int e = atomicAdd(&cnt, 1);
              if (e < LCAP) lst[e] = (ushort)((row << 9) | code);
            }
          }
        }
      }
    }
    if (phase == 0) {
      // reduce min across the 16 lanes holding the same rows (cols differ)
#pragma unroll
      for (int r = 0; r < 4; ++r) {
        m4[r] = fminf(m4[r], __shfl_xor(m4[r], 1, 64));
        m4[r] = fminf(m4[r], __shfl_xor(m4[r], 2, 64));
        m4[r] = fminf(m4[r], __shfl_xor(m4[r], 4, 64));
        m4[r] = fminf(m4[r], __shfl_xor(m4[r], 8, 64));
      }
      if ((lane & 15) == 0) {
#pragma unroll
        for (int r = 0; r < 4; ++r) rowmin[16 * wv + (lane >> 4) * 4 + r] = m4[r];
      }
      __syncthreads();
    }
  }
  __syncthreads();

  // exact rescore of candidates (scalar fp32 replica of reference)
  int n = cnt; if (n > LCAP) n = LCAP;
  for (int e = tid; e < n; e += 512) {
    int rc = lst[e];
    int row = rc >> 9, code = rc & 511;
    const float* wrow = emb + (size_t)code * D2;
    const float* zrow = zf + row * 132;
    float a = 0.f;
#pragma unroll 32
    for (int d = 0; d < D2; ++d) a = fmaf(zrow[d], wrow[d], a);
    rD[e] = fmaf(-2.f, a, __fadd_rn(xsql[row], ysql[code]));
  }
  __syncthreads();

  // per-row lexicographic first-min over candidates
  if (tid < BMR) {
    float bD = 3.4e38f; int bc = 1024;
    for (int e = 0; e < n; ++e) {
      int rc = lst[e];
      if ((rc >> 9) == tid) {
        float Dv = rD[e]; int cc = rc & 511;
        if (Dv < bD || (Dv == bD && cc < bc)) { bD = Dv; bc = cc; }
      }
    }
    idxr[tid] = bc;
    out_idx[rowBase + tid] = (float)bc;
    atomicAdd(&nt[bc], 1);
  }
  __syncthreads();

  // zq_st = z + (e - z): 8 coalesced passes
  {
    int m = tid & 15, rsub = tid >> 4;   // 32 rows per pass
#pragma unroll
    for (int p = 0; p < 8; ++p) {
      int half = p & 1;
      int row = (p >> 1) * 32 + rsub;
      int bi = idxr[row];
      float4 e4 = *(const float4*)(emb + (size_t)bi * D2 + half * DD + m * 4);
      float4 z4 = *(const float4*)&zf[row * 132 + half * DD + m * 4];
      float4 o;
      o.x = __fadd_rn(z4.x, __fsub_rn(e4.x, z4.x));
      o.y = __fadd_rn(z4.y, __fsub_rn(e4.y, z4.y));
      o.z = __fadd_rn(z4.z, __fsub_rn(e4.z, z4.z));
      o.w = __fadd_rn(z4.w, __fsub_rn(e4.w, z4.w));
      float* outp = half ? (out_zqi + (size_t)(rowBase + row) * DD + m * 4)
                         : (out_zqr + (size_t)(rowBase + row) * DD + m * 4);
      *(float4*)outp = o;
    }
  }

  // loss = 0.25 * mean((e - z)^2), numpy pairwise-8 replica
  if (tid < BMR) {
    int bi = idxr[tid];
    const float* erow = emb + (size_t)bi * D2;
    const float* zp = zf + tid * 132;
    float r8[8];
#pragma unroll
    for (int q = 0; q < 8; ++q) {
      float df = __fsub_rn(erow[q], zp[q]);
      r8[q] = __fmul_rn(df, df);
    }
    for (int m = 1; m < 16; ++m)
#pragma unroll
      for (int q = 0; q < 8; ++q) {
        float df = __fsub_rn(erow[8 * m + q], zp[8 * m + q]);
        r8[q] = __fadd_rn(r8[q], __fmul_rn(df, df));
      }
    float S = comb8(r8);
    out_loss[rowBase + tid] = __fmul_rn(0.25f, S / 128.0f);
  }
}

// ---------------- K3: dw segment-sum, LDS-staged per 32-col d-chunk
__global__ __launch_bounds__(256) void dw_scatter(const float* __restrict__ zr,
    const float* __restrict__ zi, const float* __restrict__ idxf,
    float* __restrict__ dw) {
  __shared__ float tab[KK * 32];
  int tid = threadIdx.x;
  int dc = blockIdx.x & 3;        // 4 d-chunks of 32
  int rb = blockIdx.x >> 2;       // 256 row-chunks of 1024
  for (int l = tid; l < KK * 32; l += 256) tab[l] = 0.f;
  __syncthreads();
  int r = tid >> 5, c = tid & 31;
  const float* zsrc = (dc < 2) ? zr : zi;
  int colBase = (dc & 1) * 32;
  int rowBase = rb * 1024;
  int row = rowBase + r;
  int idx = (int)idxf[row];
  float v = zsrc[(size_t)row * DD + colBase + c];
  for (int it = 0; it < 127; ++it) {
    int nrow = rowBase + (it + 1) * 8 + r;
    int nidx = (int)idxf[nrow];
    float nv = zsrc[(size_t)nrow * DD + colBase + c];
    atomicAdd(&tab[idx * 32 + c], v);
    idx = nidx; v = nv;
  }
  atomicAdd(&tab[idx * 32 + c], v);
  __syncthreads();
  for (int l = tid; l < KK * 32; l += 256) {
    int k = l >> 5, cc = l & 31;
    atomicAdd(&dw[k * D2 + dc * 32 + cc], tab[l]);
  }
}

// ---------------- K4: new_cluster, tot, cluster_size, entropy
__device__ float pw128(const float* a) {
  float r[8];
#pragma unroll
  for (int q = 0; q < 8; ++q) r[q] = a[q];
  for (int m = 1; m < 16; ++m)
#pragma unroll
    for (int q = 0; q < 8; ++q) r[q] = __fadd_rn(r[q], a[8 * m + q]);
  return comb8(r);
}

__global__ __launch_bounds__(512) void finalize_kernel(const int* __restrict__ nt,
    const float* __restrict__ ema_cs, float* __restrict__ out_ncl,
    float* __restrict__ out_ent, float* __restrict__ csize) {
  __shared__ float arr[KK];
  __shared__ float term[KK];
  __shared__ float tot_s;
  int t = threadIdx.x;
  float c = (float)nt[t];
  float newc = __fadd_rn(__fmul_rn(ema_cs[t], 0.99f), __fmul_rn(0.01f, c));
  out_ncl[t] = newc;
  arr[t] = newc;
  float p = c / 262144.f;
  term[t] = __fmul_rn(p, logf(__fadd_rn(p, 1e-10f)));
  __syncthreads();
  if (t == 0) {
    float tot = __fadd_rn(__fadd_rn(pw128(arr), pw128(arr + 128)),
                          __fadd_rn(pw128(arr + 256), pw128(arr + 384)));
    tot_s = tot;
    float S = __fadd_rn(__fadd_rn(pw128(term), pw128(term + 128)),
                        __fadd_rn(pw128(term + 256), pw128(term + 384)));
    out_ent[0] = __fdiv_rn(-S, 6.2383246250395075f);  // / log(512)
  }
  __syncthreads();
  float tot = tot_s;
  float cs = __fmul_rn(__fdiv_rn(__fadd_rn(arr[t], 1e-5f), __fadd_rn(tot, 0.00512f)), tot);
  csize[t] = cs;
}

// ---------------- K5: new_ema_w, new_emb_w
__global__ __launch_bounds__(256) void ema_out_kernel(const float* __restrict__ ema_w,
    const float* __restrict__ dw, const float* __restrict__ csize,
    float* __restrict__ out_ema, float* __restrict__ out_emb) {
  int t = blockIdx.x * 256 + threadIdx.x;   // 65536
  float e = __fadd_rn(__fmul_rn(ema_w[t], 0.99f), __fmul_rn(0.01f, dw[t]));
  out_ema[t] = e;
  out_emb[t] = __fdiv_rn(e, csize[t >> 7]);
}

extern "C" void kernel_launch(void* const* d_in, const int* in_sizes, int n_in,
                              void* d_out, int out_size, void* d_ws, size_t ws_size,
                              hipStream_t stream) {
  const float* zr     = (const float*)d_in[0];
  const float* zi     = (const float*)d_in[1];
  const float* emb    = (const float*)d_in[2];
  const float* ema_cs = (const float*)d_in[3];
  const float* ema_w  = (const float*)d_in[4];
  float* out = (float*)d_out;

  float* wsf   = (float*)d_ws;
  float* ysq   = wsf;            // 512
  float* csize = wsf + 512;      // 512
  int*   nt    = (int*)(wsf + 1024);  // 512
  float* dw    = wsf + 1536;     // 65536

  prep_kernel<<<256, 256, 0, stream>>>(emb, ysq, nt, dw);
  vq_mfma<<<NROWS / BMR, 512, 0, stream>>>(zr, zi, emb, ysq,
      out + O_ZQR, out + O_ZQI, out + O_LOSS, out + O_IDX, nt);
  dw_scatter<<<1024, 256, 0, stream>>>(zr, zi, out + O_IDX, dw);
  finalize_kernel<<<1, 512, 0, stream>>>(nt, ema_cs, out + O_NCL, out + O_ENT, csize);
  ema_out_kernel<<<256, 256, 0, stream>>>(ema_w, dw, csize, out + O_EMA, out + O_EMB);
}

// Round 8
// 638.109 us; speedup vs baseline: 1.5376x; 1.2475x over previous
//
#include <hip/hip_runtime.h>

#define NROWS 262144
#define DD 64
#define D2 128
#define KK 512

// output offsets (floats)
#define O_ZQR 0
#define O_ZQI 16777216
#define O_LOSS 33554432
#define O_IDX 33816576
#define O_ENT 34078720
#define O_EMB 34078721
#define O_NCL 34144257
#define O_EMA 34144769

typedef __bf16 bf16x8 __attribute__((ext_vector_type(8)));
typedef float f32x4 __attribute__((ext_vector_type(4)));

// numpy pairwise-8 final combine
__device__ __forceinline__ float comb8(const float r[8]) {
  return __fadd_rn(__fadd_rn(__fadd_rn(r[0], r[1]), __fadd_rn(r[2], r[3])),
                   __fadd_rn(__fadd_rn(r[4], r[5]), __fadd_rn(r[6], r[7])));
}

// fp32 -> bf16 RNE (bit trick; no NaN/inf in data)
__device__ __forceinline__ ushort f2bf(float x) {
  union { float f; unsigned u; } a; a.f = x;
  unsigned r = (a.u + 0x7FFFu + ((a.u >> 16) & 1u)) >> 16;
  return (ushort)r;
}

// ---------------- K1: zero dw/n_total, emb->bf16, y_sq (numpy pairwise-8)
__global__ __launch_bounds__(256) void prep_kernel(const float* __restrict__ emb,
    float* __restrict__ ysq, int* __restrict__ nt, float* __restrict__ dw,
    ushort* __restrict__ embbf) {
  int t = blockIdx.x * 256 + threadIdx.x;   // 65536 threads
  dw[t] = 0.f;
  embbf[t] = f2bf(emb[t]);
  if (t < KK) {
    nt[t] = 0;
    const float* a = emb + t * D2;
    float r[8];
#pragma unroll
    for (int q = 0; q < 8; ++q) { float v = a[q]; r[q] = __fmul_rn(v, v); }
    for (int m = 1; m < 16; ++m)
#pragma unroll
      for (int q = 0; q < 8; ++q) { float v = a[8 * m + q]; r[q] = __fadd_rn(r[q], __fmul_rn(v, v)); }
    ysq[t] = comb8(r);
  }
}

// ---------------- K2: MFMA filter + exact rescore + epilogue
// 512 thr / 8 waves, 128 rows/block. 8 passes (2 phases x 4 chunks of 128
// codes); Bb ping-pong double-buffer with issue-early/write-late staging so
// L2 loads hide under MFMA. Phase 0: per-row min of s~ = ysq - 2*(z.w)_bf16.
// Phase 1: list codes with s~ <= rowmin + DELTA (superset of exact fl-argmin:
// phase-1 s~ is bit-identical to phase-0 s~, so the min-code always passes).
// Exact fp32 rescore (global reads, BLAS-order seq-fmaf) + packed 64-bit
// atomicMin (dist>0 => float-bit order == value order; low bits = code ->
// first-index tie-break preserved).
#define BMR 128
#define DELTA 1e-3f
#define LCAP 2048
#define BST 136   // Bb ushort stride (272B rows: benign 2-way banks on frag reads)

__global__ __launch_bounds__(512, 2) void vq_mfma(
    const float* __restrict__ zr, const float* __restrict__ zi,
    const float* __restrict__ emb, const ushort* __restrict__ embbf,
    const float* __restrict__ ysq,
    float* __restrict__ out_zqr, float* __restrict__ out_zqi,
    float* __restrict__ out_loss, float* __restrict__ out_idx,
    int* __restrict__ nt) {
  __shared__ __align__(16) float zf[BMR * 132];      // z fp32, padded stride
  __shared__ __align__(16) ushort Bb[2][128 * BST];  // codebook bf16, ping-pong
  __shared__ float ysql[KK];
  __shared__ float xsql[BMR];
  __shared__ float rowmin[BMR];
  __shared__ unsigned long long rowbest[BMR];
  __shared__ ushort lst[LCAP];
  __shared__ int cnt;
  __shared__ int idxr[BMR];

  const int tid = threadIdx.x;
  const int rowBase = blockIdx.x * BMR;
  const int wv = tid >> 6;
  const int lane = tid & 63;

  // stage z tile fp32: zf[row][0..63]=real, [64..127]=imag
#pragma unroll
  for (int r = 0; r < 8; ++r) {
    int fidx = r * 512 + tid;       // 4096 float4
    int row = fidx >> 5, g = fidx & 31;
    float4 v;
    if (g < 16) v = *(const float4*)(zr + (size_t)(rowBase + row) * DD + g * 4);
    else        v = *(const float4*)(zi + (size_t)(rowBase + row) * DD + (g - 16) * 4);
    *(float4*)&zf[row * 132 + g * 4] = v;
  }
  // stage chunk 0 codebook (bf16, precomputed) into Bb[0]:
  // 128 rows x 16 slots of 16B (one row = 128 ushorts = 16 uint4)
#pragma unroll
  for (int it = 0; it < 4; ++it) {
    int gidx = it * 512 + tid;      // 2048 slots
    int row = gidx >> 4, slot = gidx & 15;
    *(uint4*)&Bb[0][row * BST + slot * 8] =
        *(const uint4*)(embbf + (size_t)row * D2 + slot * 8);
  }
  ysql[tid] = ysq[tid];
  if (tid < BMR) rowbest[tid] = ~0ull;
  if (tid == 0) cnt = 0;
  __syncthreads();

  // x_sq per row (numpy pairwise-8 replica)
  if (tid < BMR) {
    const float* zp = zf + tid * 132;
    float r8[8];
#pragma unroll
    for (int q = 0; q < 8; ++q) { float z = zp[q]; r8[q] = __fmul_rn(z, z); }
    for (int m = 1; m < 16; ++m)
#pragma unroll
      for (int q = 0; q < 8; ++q) { float z = zp[8 * m + q]; r8[q] = __fadd_rn(r8[q], __fmul_rn(z, z)); }
    xsql[tid] = comb8(r8);
  }

  // A-fragments (persistent): lane holds row (lane&15), k-octet (lane>>4)
  bf16x8 af[4];
  {
    int arow = 16 * wv + (lane & 15);
#pragma unroll
    for (int t4 = 0; t4 < 4; ++t4) {
      union { ushort u[8]; bf16x8 v; } a;
#pragma unroll
      for (int e = 0; e < 8; ++e)
        a.u[e] = f2bf(zf[arow * 132 + t4 * 32 + (lane >> 4) * 8 + e]);
      af[t4] = a.v;
    }
  }

  float m4[4] = {3.4e38f, 3.4e38f, 3.4e38f, 3.4e38f};

#pragma unroll 1
  for (int p = 0; p < 8; ++p) {
    // issue-early: loads for next pass's chunk (hide L2 latency under MFMA)
    const int cNext = (p + 1) & 3;
    uint4 stg0, stg1, stg2, stg3;
    if (p < 7) {
      int row0 = tid >> 3, seg = tid & 7;   // rows 0..63 / slot pairs
      const uint4* src = (const uint4*)(embbf + (size_t)cNext * 128 * D2);
      stg0 = src[(size_t)row0 * 16 + seg];            // rows 0..63,   slots 0..7
      stg1 = src[(size_t)(row0 + 64) * 16 + seg];     // rows 64..127, slots 0..7
      stg2 = src[(size_t)row0 * 16 + seg + 8];        // rows 0..63,   slots 8..15
      stg3 = src[(size_t)(row0 + 64) * 16 + seg + 8]; // rows 64..127, slots 8..15
    }
    const ushort* Bp = &Bb[p & 1][0];
    f32x4 acc[8];
#pragma unroll
    for (int j = 0; j < 8; ++j) acc[j] = (f32x4){0.f, 0.f, 0.f, 0.f};
#pragma unroll
    for (int j = 0; j < 8; ++j)
#pragma unroll
      for (int t4 = 0; t4 < 4; ++t4) {
        bf16x8 bv = *(const bf16x8*)&Bp[(j * 16 + (lane & 15)) * BST + t4 * 32 + (lane >> 4) * 8];
        acc[j] = __builtin_amdgcn_mfma_f32_16x16x32_bf16(af[t4], bv, acc[j], 0, 0, 0);
      }

    if (p < 4) {
#pragma unroll
      for (int j = 0; j < 8; ++j) {
        float y = ysql[(p & 3) * 128 + j * 16 + (lane & 15)];
#pragma unroll
        for (int r = 0; r < 4; ++r)
          m4[r] = fminf(m4[r], fmaf(-2.f, acc[j][r], y));
      }
      if (p == 3) {
        // reduce min across the 16 lanes holding the same rows (cols differ)
#pragma unroll
        for (int r = 0; r < 4; ++r) {
          m4[r] = fminf(m4[r], __shfl_xor(m4[r], 1, 64));
          m4[r] = fminf(m4[r], __shfl_xor(m4[r], 2, 64));
          m4[r] = fminf(m4[r], __shfl_xor(m4[r], 4, 64));
          m4[r] = fminf(m4[r], __shfl_xor(m4[r], 8, 64));
        }
        if ((lane & 15) == 0) {
#pragma unroll
          for (int r = 0; r < 4; ++r) rowmin[16 * wv + (lane >> 4) * 4 + r] = m4[r];
        }
      }
    } else {
#pragma unroll
      for (int j = 0; j < 8; ++j) {
        int code = (p & 3) * 128 + j * 16 + (lane & 15);
        float y = ysql[code];
#pragma unroll
        for (int r = 0; r < 4; ++r) {
          float s = fmaf(-2.f, acc[j][r], y);
          int row = 16 * wv + (lane >> 4) * 4 + r;
          if (s <= rowmin[row] + DELTA) {
            int e = atomicAdd(&cnt, 1);
            if (e < LCAP) lst[e] = (ushort)((row << 9) | code);
          }
        }
      }
    }

    // write-late: commit next chunk into the other buffer.
    // Safe vs pass p-1 readers of this buffer: they finished at the p-1
    // end-of-pass barrier.
    if (p < 7) {
      ushort* Bw = &Bb[(p + 1) & 1][0];
      int row0 = tid >> 3, seg = tid & 7;
      *(uint4*)&Bw[(size_t)row0 * BST + seg * 8] = stg0;
      *(uint4*)&Bw[(size_t)(row0 + 64) * BST + seg * 8] = stg1;
      *(uint4*)&Bw[(size_t)row0 * BST + (seg + 8) * 8] = stg2;
      *(uint4*)&Bw[(size_t)(row0 + 64) * BST + (seg + 8) * 8] = stg3;
    }
    __syncthreads();
  }

  // exact rescore of candidates: global z/w (L2/L3-hot), packed atomicMin.
  // Sequential fmaf over d=0..127 (concat real,imag) = BLAS micro-kernel
  // order; bit-identical to the r3/r5/r6-passing path.
  int n = cnt; if (n > LCAP) n = LCAP;
  for (int e = tid; e < n; e += 512) {
    int rc = lst[e];
    int row = rc >> 9, code = rc & 511;
    const float* wrow = emb + (size_t)code * D2;
    const float* zrr = zr + (size_t)(rowBase + row) * DD;
    const float* zii = zi + (size_t)(rowBase + row) * DD;
    float a = 0.f;
#pragma unroll 16
    for (int d = 0; d < DD; ++d) a = fmaf(zrr[d], wrow[d], a);
#pragma unroll 16
    for (int d = 0; d < DD; ++d) a = fmaf(zii[d], wrow[DD + d], a);
    float Dv = fmaf(-2.f, a, __fadd_rn(xsql[row], ysql[code]));
    unsigned long long pack =
        ((unsigned long long)__float_as_uint(Dv) << 32) | (unsigned)code;
    atomicMin(&rowbest[row], pack);
  }
  __syncthreads();

  if (tid < BMR) {
    int bc = (int)(rowbest[tid] & 0xFFFFFFFFull);
    idxr[tid] = bc;
    out_idx[rowBase + tid] = (float)bc;
    atomicAdd(&nt[bc], 1);
  }
  __syncthreads();

  // zq_st = z + (e - z): 8 coalesced passes
  {
    int m = tid & 15, rsub = tid >> 4;   // 32 rows per pass
#pragma unroll
    for (int p = 0; p < 8; ++p) {
      int half = p & 1;
      int row = (p >> 1) * 32 + rsub;
      int bi = idxr[row];
      float4 e4 = *(const float4*)(emb + (size_t)bi * D2 + half * DD + m * 4);
      float4 z4 = *(const float4*)&zf[row * 132 + half * DD + m * 4];
      float4 o;
      o.x = __fadd_rn(z4.x, __fsub_rn(e4.x, z4.x));
      o.y = __fadd_rn(z4.y, __fsub_rn(e4.y, z4.y));
      o.z = __fadd_rn(z4.z, __fsub_rn(e4.z, z4.z));
      o.w = __fadd_rn(z4.w, __fsub_rn(e4.w, z4.w));
      float* outp = half ? (out_zqi + (size_t)(rowBase + row) * DD + m * 4)
                         : (out_zqr + (size_t)(rowBase + row) * DD + m * 4);
      *(float4*)outp = o;
    }
  }

  // loss = 0.25 * mean((e - z)^2), numpy pairwise-8 replica
  if (tid < BMR) {
    int bi = idxr[tid];
    const float* erow = emb + (size_t)bi * D2;
    const float* zp = zf + tid * 132;
    float r8[8];
#pragma unroll
    for (int q = 0; q < 8; ++q) {
      float df = __fsub_rn(erow[q], zp[q]);
      r8[q] = __fmul_rn(df, df);
    }
    for (int m = 1; m < 16; ++m)
#pragma unroll
      for (int q = 0; q < 8; ++q) {
        float df = __fsub_rn(erow[8 * m + q], zp[8 * m + q]);
        r8[q] = __fadd_rn(r8[q], __fmul_rn(df, df));
      }
    float S = comb8(r8);
    out_loss[rowBase + tid] = __fmul_rn(0.25f, S / 128.0f);
  }
}

// ---------------- K3: dw segment-sum, LDS-staged per 32-col d-chunk
__global__ __launch_bounds__(256) void dw_scatter(const float* __restrict__ zr,
    const float* __restrict__ zi, const float* __restrict__ idxf,
    float* __restrict__ dw) {
  __shared__ float tab[KK * 32];
  int tid = threadIdx.x;
  int dc = blockIdx.x & 3;        // 4 d-chunks of 32
  int rb = blockIdx.x >> 2;       // 256 row-chunks of 1024
  for (int l = tid; l < KK * 32; l += 256) tab[l] = 0.f;
  __syncthreads();
  int r = tid >> 5, c = tid & 31;
  const float* zsrc = (dc < 2) ? zr : zi;
  int colBase = (dc & 1) * 32;
  int rowBase = rb * 1024;
  int row = rowBase + r;
  int idx = (int)idxf[row];
  float v = zsrc[(size_t)row * DD + colBase + c];
  for (int it = 0; it < 127; ++it) {
    int nrow = rowBase + (it + 1) * 8 + r;
    int nidx = (int)idxf[nrow];
    float nv = zsrc[(size_t)nrow * DD + colBase + c];
    atomicAdd(&tab[idx * 32 + c], v);
    idx = nidx; v = nv;
  }
  atomicAdd(&tab[idx * 32 + c], v);
  __syncthreads();
  for (int l = tid; l < KK * 32; l += 256) {
    int k = l >> 5, cc = l & 31;
    atomicAdd(&dw[k * D2 + dc * 32 + cc], tab[l]);
  }
}

// ---------------- K4: new_cluster, tot, cluster_size, entropy
__device__ float pw128(const float* a) {
  float r[8];
#pragma unroll
  for (int q = 0; q < 8; ++q) r[q] = a[q];
  for (int m = 1; m < 16; ++m)
#pragma unroll
    for (int q = 0; q < 8; ++q) r[q] = __fadd_rn(r[q], a[8 * m + q]);
  return comb8(r);
}

__global__ __launch_bounds__(512) void finalize_kernel(const int* __restrict__ nt,
    const float* __restrict__ ema_cs, float* __restrict__ out_ncl,
    float* __restrict__ out_ent, float* __restrict__ csize) {
  __shared__ float arr[KK];
  __shared__ float term[KK];
  __shared__ float tot_s;
  int t = threadIdx.x;
  float c = (float)nt[t];
  float newc = __fadd_rn(__fmul_rn(ema_cs[t], 0.99f), __fmul_rn(0.01f, c));
  out_ncl[t] = newc;
  arr[t] = newc;
  float p = c / 262144.f;
  term[t] = __fmul_rn(p, logf(__fadd_rn(p, 1e-10f)));
  __syncthreads();
  if (t == 0) {
    float tot = __fadd_rn(__fadd_rn(pw128(arr), pw128(arr + 128)),
                          __fadd_rn(pw128(arr + 256), pw128(arr + 384)));
    tot_s = tot;
    float S = __fadd_rn(__fadd_rn(pw128(term), pw128(term + 128)),
                        __fadd_rn(pw128(term + 256), pw128(term + 384)));
    out_ent[0] = __fdiv_rn(-S, 6.2383246250395075f);  // / log(512)
  }
  __syncthreads();
  float tot = tot_s;
  float cs = __fmul_rn(__fdiv_rn(__fadd_rn(arr[t], 1e-5f), __fadd_rn(tot, 0.00512f)), tot);
  csize[t] = cs;
}

// ---------------- K5: new_ema_w, new_emb_w
__global__ __launch_bounds__(256) void ema_out_kernel(const float* __restrict__ ema_w,
    const float* __restrict__ dw, const float* __restrict__ csize,
    float* __restrict__ out_ema, float* __restrict__ out_emb) {
  int t = blockIdx.x * 256 + threadIdx.x;   // 65536
  float e = __fadd_rn(__fmul_rn(ema_w[t], 0.99f), __fmul_rn(0.01f, dw[t]));
  out_ema[t] = e;
  out_emb[t] = __fdiv_rn(e, csize[t >> 7]);
}

extern "C" void kernel_launch(void* const* d_in, const int* in_sizes, int n_in,
                              void* d_out, int out_size, void* d_ws, size_t ws_size,
                              hipStream_t stream) {
  const float* zr     = (const float*)d_in[0];
  const float* zi     = (const float*)d_in[1];
  const float* emb    = (const float*)d_in[2];
  const float* ema_cs = (const float*)d_in[3];
  const float* ema_w  = (const float*)d_in[4];
  float* out = (float*)d_out;

  float* wsf   = (float*)d_ws;
  float* ysq   = wsf;                     // 512
  float* csize = wsf + 512;               // 512
  int*   nt    = (int*)(wsf + 1024);      // 512
  float* dw    = wsf + 1536;              // 65536
  ushort* embbf = (ushort*)(wsf + 67072); // 65536 ushorts (128KB)

  prep_kernel<<<256, 256, 0, stream>>>(emb, ysq, nt, dw, embbf);
  vq_mfma<<<NROWS / BMR, 512, 0, stream>>>(zr, zi, emb, embbf, ysq,
      out + O_ZQR, out + O_ZQI, out + O_LOSS, out + O_IDX, nt);
  dw_scatter<<<1024, 256, 0, stream>>>(zr, zi, out + O_IDX, dw);
  finalize_kernel<<<1, 512, 0, stream>>>(nt, ema_cs, out + O_NCL, out + O_ENT, csize);
  ema_out_kernel<<<256, 256, 0, stream>>>(ema_w, dw, csize, out + O_EMA, out + O_EMB);
}